// Round 3
// baseline (1268.387 us; speedup 1.0000x reference)
//
#include <hip/hip_runtime.h>
#include <hip/hip_bf16.h>

#define D 128
#define TM 64
#define APITCH 136   // bf16 elems per LDS A row (272B rows -> 2-way bank alias, free)

typedef __attribute__((ext_vector_type(8))) short short8;
typedef __attribute__((ext_vector_type(4))) float f32x4;
typedef __attribute__((ext_vector_type(2))) float f32x2;

__device__ __forceinline__ short f2bf(float f) {
    union { float f; unsigned u; } v; v.f = f;
    unsigned r = v.u + 0x7fffu + ((v.u >> 16) & 1u);  // RNE
    return (short)(r >> 16);
}
__device__ __forceinline__ float bflo(unsigned v) {
    union { unsigned u; float f; } t; t.u = v << 16; return t.f;
}
__device__ __forceinline__ float bfhi(unsigned v) {
    union { unsigned u; float f; } t; t.u = v & 0xffff0000u; return t.f;
}

struct TileLDS {
    short A[TM * APITCH];     // 17408 B  bf16 A-tile (MFMA A operand)
    f32x2 red[TM][4][4];      // 8192 B   [row][wave][subgroup] partial (sum, sumsq)
    f32x2 mr[TM];             // 512 B    per-row (mean, rstd)
    int hi_s[TM];
    int wi_s[TM];
};

__device__ __forceinline__ short8 load_bfrag(const float* p) {
    short8 r;
#pragma unroll
    for (int j = 0; j < 8; ++j) r[j] = f2bf(p[j]);
    return r;
}

// Per-wave B fragments: wave owns 32 output channels of Y = X @ W^T.
__device__ __forceinline__ void load_wset(const float* W, int pitch, int n0, int lr, int kh,
                                          short8 frag[2][4]) {
#pragma unroll
    for (int t = 0; t < 2; ++t)
#pragma unroll
        for (int ks = 0; ks < 4; ++ks)
            frag[t][ks] = load_bfrag(W + (size_t)(n0 + t * 16 + lr) * pitch + ks * 32 + kh * 8);
}

// Wave computes 64 rows x 32 cols of Y = A(64x128) @ W^T, f32 acc.
__device__ __forceinline__ void wave_gemm(const short* A, const short8 frag[2][4],
                                          int lr, int kh, f32x4 acc[4][2]) {
#pragma unroll
    for (int mt = 0; mt < 4; ++mt)
#pragma unroll
        for (int t = 0; t < 2; ++t)
            acc[mt][t] = (f32x4){0.f, 0.f, 0.f, 0.f};
#pragma unroll
    for (int ks = 0; ks < 4; ++ks) {
        short8 a[4];
#pragma unroll
        for (int mt = 0; mt < 4; ++mt)
            a[mt] = *(const short8*)&A[(mt * 16 + lr) * APITCH + ks * 32 + kh * 8];
#pragma unroll
        for (int mt = 0; mt < 4; ++mt)
#pragma unroll
            for (int t = 0; t < 2; ++t)
                acc[mt][t] = __builtin_amdgcn_mfma_f32_16x16x32_bf16(a[mt], frag[t][ks], acc[mt][t], 0, 0, 0);
    }
}

__device__ __forceinline__ void store_acc_global(float* Y, long rbase, int M,
                                                 const f32x4 acc[4][2], int lane, int w) {
    int lr = lane & 15, hh = lane >> 4;
#pragma unroll
    for (int mt = 0; mt < 4; ++mt)
#pragma unroll
        for (int t = 0; t < 2; ++t)
#pragma unroll
            for (int r = 0; r < 4; ++r) {
                int row = mt * 16 + hh * 4 + r;
                if (rbase + row < M)
                    Y[(size_t)(rbase + row) * D + w * 32 + t * 16 + lr] = acc[mt][t][r];
            }
}

// In-register GN stats from acc: butterfly (masks 1,2) -> subgroup partials -> LDS red
// -> per-row mean/rstd in L.mr. Contains 2 syncthreads; call from all threads.
__device__ __forceinline__ void gn_stats(TileLDS& L, const f32x4 acc[4][2],
                                         int tid, int lane, int w) {
    int lr = lane & 15, hh = lane >> 4;
#pragma unroll
    for (int mt = 0; mt < 4; ++mt)
#pragma unroll
        for (int r = 0; r < 4; ++r) {
            float s = acc[mt][0][r] + acc[mt][1][r];
            float q = acc[mt][0][r] * acc[mt][0][r] + acc[mt][1][r] * acc[mt][1][r];
            s += __shfl_xor(s, 1); q += __shfl_xor(q, 1);
            s += __shfl_xor(s, 2); q += __shfl_xor(q, 2);
            if ((lr & 3) == mt) {
                int row = mt * 16 + hh * 4 + r;
                L.red[row][w][lr >> 2] = (f32x2){s, q};
            }
        }
    __syncthreads();
    if (tid < TM) {
        float s = 0.f, q = 0.f;
        const f32x2* p = (const f32x2*)L.red[tid];
#pragma unroll
        for (int i = 0; i < 16; ++i) { f32x2 v = p[i]; s += v[0]; q += v[1]; }
        float mu = s * (1.f / 128.f);
        float var = q * (1.f / 128.f) - mu * mu;
        L.mr[tid] = (f32x2){mu, rsqrtf(var + 1e-5f)};
    }
    __syncthreads();
}

// Full in-register GN: stats + normalize + relu + write bf16 A-tile. 3 syncs total.
__device__ __forceinline__ void gn_reg(TileLDS& L, const f32x4 acc[4][2],
                                       float gw0, float gb0, float gw1, float gb1,
                                       int tid, int lane, int w) {
    gn_stats(L, acc, tid, lane, w);
    int lr = lane & 15, hh = lane >> 4, n0 = w * 32;
#pragma unroll
    for (int mt = 0; mt < 4; ++mt)
#pragma unroll
        for (int r = 0; r < 4; ++r) {
            int row = mt * 16 + hh * 4 + r;
            f32x2 m = L.mr[row];
            float v0 = (acc[mt][0][r] - m[0]) * m[1] * gw0 + gb0;
            float v1 = (acc[mt][1][r] - m[0]) * m[1] * gw1 + gb1;
            L.A[row * APITCH + n0 + lr]      = f2bf(fmaxf(v0, 0.f));
            L.A[row * APITCH + n0 + 16 + lr] = f2bf(fmaxf(v1, 0.f));
        }
    __syncthreads();
}

__device__ __forceinline__ void stage_rows_to_A(TileLDS& L, const float* X, long rbase, int M, int tid) {
#pragma unroll
    for (int it = 0; it < 8; ++it) {
        int chunk = tid + it * 256;
        int row = chunk >> 5, c4 = chunk & 31;
        long r = rbase + row;
        float4 v = (r < M) ? *(const float4*)&X[(size_t)r * D + c4 * 4] : make_float4(0.f, 0.f, 0.f, 0.f);
        short* a = &L.A[row * APITCH + c4 * 4];
        a[0] = f2bf(v.x); a[1] = f2bf(v.y); a[2] = f2bf(v.z); a[3] = f2bf(v.w);
    }
}

// ---------------- CSR build: histogram -> scan -> fill ----------------
__global__ void k_hist(const int* __restrict__ hi, int* __restrict__ cnt, int E) {
    int i = blockIdx.x * 256 + threadIdx.x;
    if (i < E) atomicAdd(&cnt[hi[i]], 1);
}

// Single-block sequential chunked exclusive scan over n counters.
__global__ void k_scan(const int* __restrict__ cnt, int* __restrict__ offs,
                       int* __restrict__ cursor, int n) {
    __shared__ int wsum[4];
    __shared__ int carry_s;
    int tid = threadIdx.x, lane = tid & 63, w = tid >> 6;
    if (tid == 0) carry_s = 0;
    __syncthreads();
    for (int base = 0; base < n; base += 256) {
        int i = base + tid;
        int v = (i < n) ? cnt[i] : 0;
        int x = v;
#pragma unroll
        for (int d = 1; d < 64; d <<= 1) {
            int t = __shfl_up(x, d);
            if (lane >= d) x += t;
        }
        if (lane == 63) wsum[w] = x;
        __syncthreads();
        int woff = 0;
        for (int j = 0; j < w; ++j) woff += wsum[j];
        int carry = carry_s;
        int excl = carry + woff + x - v;
        if (i < n) { offs[i] = excl; cursor[i] = excl; }
        __syncthreads();
        if (tid == 255) carry_s = carry + woff + x;
        __syncthreads();
    }
    if (tid == 0) offs[n] = carry_s;
}

__global__ void k_fill(const int* __restrict__ hi, int* __restrict__ cursor,
                       int* __restrict__ eidx, int E) {
    int i = blockIdx.x * 256 + threadIdx.x;
    if (i < E) {
        int p = atomicAdd(&cursor[hi[i]], 1);
        eidx[p] = i;
    }
}

// ---------------- kernel 1: agent-side precompute ----------------
// abuf = agts @ Wa^T ; qa = relu(GN(agts @ Wq^T)) ; qpart = qa @ Wc1_q^T
__global__ __launch_bounds__(256, 3)
void k_qpath(const float* __restrict__ agts,
             const float* __restrict__ Wq, const float* __restrict__ gqw, const float* __restrict__ gqb,
             const float* __restrict__ Wc1, const float* __restrict__ Wa,
             float* __restrict__ qpart, float* __restrict__ abuf, int M, int ntiles) {
    __shared__ TileLDS L;
    int tid = threadIdx.x;
    int lane = tid & 63, w = tid >> 6;
    int lr = lane & 15, kh = lane >> 4;
    int n0 = w * 32;
    short8 fa[2][4], fq[2][4], fcq[2][4];
    load_wset(Wa, 128, n0, lr, kh, fa);
    load_wset(Wq, 128, n0, lr, kh, fq);
    load_wset(Wc1 + 128, 384, n0, lr, kh, fcq);  // q-part cols 128..255
    float gw0 = gqw[n0 + lr], gw1 = gqw[n0 + 16 + lr];
    float gb0 = gqb[n0 + lr], gb1 = gqb[n0 + 16 + lr];

    for (int tile = blockIdx.x; tile < ntiles; tile += gridDim.x) {
        long rbase = (long)tile * TM;
        stage_rows_to_A(L, agts, rbase, M, tid);
        __syncthreads();
        f32x4 acc[4][2];
        wave_gemm(L.A, fa, lr, kh, acc);
        store_acc_global(abuf, rbase, M, acc, lane, w);
        wave_gemm(L.A, fq, lr, kh, acc);
        gn_reg(L, acc, gw0, gb0, gw1, gb1, tid, lane, w);
        wave_gemm(L.A, fcq, lr, kh, acc);
        store_acc_global(qpart, rbase, M, acc, lane, w);
        __syncthreads();
    }
}

// ---------------- kernel 2: ctx precompute ----------------
__global__ __launch_bounds__(256, 4)
void k_ctx(const float* __restrict__ ctx, const float* __restrict__ Wc1,
           float* __restrict__ cpart, int M, int ntiles) {
    __shared__ TileLDS L;
    int tid = threadIdx.x;
    int lane = tid & 63, w = tid >> 6;
    int lr = lane & 15, kh = lane >> 4;
    short8 fc[2][4];
    load_wset(Wc1 + 256, 384, w * 32, lr, kh, fc);  // ctx-part cols 256..383
    for (int tile = blockIdx.x; tile < ntiles; tile += gridDim.x) {
        long rbase = (long)tile * TM;
        stage_rows_to_A(L, ctx, rbase, M, tid);
        __syncthreads();
        f32x4 acc[4][2];
        wave_gemm(L.A, fc, lr, kh, acc);
        store_acc_global(cpart, rbase, M, acc, lane, w);
        __syncthreads();
    }
}

// ---------------- kernel 3: fused edge pipeline (atomic-free) ----------------
__global__ __launch_bounds__(256, 3)
void k_edge(const float* __restrict__ agt_ctrs, const float* __restrict__ ctx_ctrs,
            const int* __restrict__ hi, const int* __restrict__ wi,
            const float* __restrict__ Wd1, const float* __restrict__ bd1,
            const float* __restrict__ Wd2, const float* __restrict__ gd2w, const float* __restrict__ gd2b,
            const float* __restrict__ Wc1, const float* __restrict__ gc1w, const float* __restrict__ gc1b,
            const float* __restrict__ Wc2,
            const float* __restrict__ qpart, const float* __restrict__ cpart,
            short* __restrict__ ebuf, int E, int ntiles) {
    __shared__ TileLDS L;
    int tid = threadIdx.x;
    int lane = tid & 63, w = tid >> 6;
    int lr = lane & 15, kh = lane >> 4;
    int n0 = w * 32;
    short8 fd2[2][4], fc1[2][4], fc2[2][4];
    load_wset(Wd2, 128, n0, lr, kh, fd2);
    load_wset(Wc1, 384, n0, lr, kh, fc1);  // d-part cols 0..127
    load_wset(Wc2, 128, n0, lr, kh, fc2);
    float g2w0 = gd2w[n0 + lr], g2w1 = gd2w[n0 + 16 + lr];
    float g2b0 = gd2b[n0 + lr], g2b1 = gd2b[n0 + 16 + lr];
    float g1w0 = gc1w[n0 + lr], g1w1 = gc1w[n0 + 16 + lr];
    float g1b0 = gc1b[n0 + lr], g1b1 = gc1b[n0 + 16 + lr];

    for (int tile = blockIdx.x; tile < ntiles; tile += gridDim.x) {
        long ebase = (long)tile * TM;
        if (tid < TM) {
            long e = ebase + tid;
            L.hi_s[tid] = (e < E) ? hi[e] : 0;
            L.wi_s[tid] = (e < E) ? wi[e] : 0;
        }
        // d2 = relu(dd @ Wd1^T + bd1) -> bf16 A-tile (thread: one row, 32 chans)
        {
            int row = tid >> 2, q4 = tid & 3;
            long e = ebase + row;
            bool valid = e < E;
            float dd0 = 0.f, dd1 = 0.f;
            if (valid) {
                int h = hi[e], c = wi[e];
                dd0 = agt_ctrs[h * 2 + 0] - ctx_ctrs[c * 2 + 0];
                dd1 = agt_ctrs[h * 2 + 1] - ctx_ctrs[c * 2 + 1];
            }
#pragma unroll
            for (int cb = 0; cb < 4; ++cb) {
                short8 ov;
#pragma unroll
                for (int j = 0; j < 8; ++j) {
                    int c = q4 * 32 + cb * 8 + j;
                    float v = valid ? fmaxf(Wd1[c * 2 + 0] * dd0 + Wd1[c * 2 + 1] * dd1 + bd1[c], 0.f) : 0.f;
                    ov[j] = f2bf(v);
                }
                *(short8*)&L.A[row * APITCH + q4 * 32 + cb * 8] = ov;
            }
        }
        __syncthreads();
        f32x4 acc[4][2];
        wave_gemm(L.A, fd2, lr, kh, acc);                 // t = d2 @ Wd2^T
        gn_reg(L, acc, g2w0, g2b0, g2w1, g2b1, tid, lane, w);  // d = relu(GN(t)) -> A
        wave_gemm(L.A, fc1, lr, kh, acc);                 // d @ Wc1_d^T
        // + qpart[hi] + cpart[wi], folded into acc layout
#pragma unroll
        for (int mt = 0; mt < 4; ++mt)
#pragma unroll
            for (int r = 0; r < 4; ++r) {
                int row = mt * 16 + kh * 4 + r;
                const float* qp = qpart + (size_t)L.hi_s[row] * D;
                const float* cp = cpart + (size_t)L.wi_s[row] * D;
                acc[mt][0][r] += qp[n0 + lr]      + cp[n0 + lr];
                acc[mt][1][r] += qp[n0 + 16 + lr] + cp[n0 + 16 + lr];
            }
        gn_reg(L, acc, g1w0, g1b0, g1w1, g1b1, tid, lane, w);  // relu(GN(.)) -> A
        wave_gemm(L.A, fc2, lr, kh, acc);                 // cout = cmid @ Wc2^T
        // store message rows bf16 (fire-and-forget, no atomics)
#pragma unroll
        for (int mt = 0; mt < 4; ++mt)
#pragma unroll
            for (int r = 0; r < 4; ++r) {
                int erow = mt * 16 + kh * 4 + r;
                long e = ebase + erow;
                if (e < E) {
                    short* dst = ebuf + (size_t)e * D;
                    dst[n0 + lr]      = f2bf(acc[mt][0][r]);
                    dst[n0 + 16 + lr] = f2bf(acc[mt][1][r]);
                }
            }
        __syncthreads();
    }
}

// ---------------- kernel 3b: per-agent gather-reduce (one wave per agent) ----------------
__global__ __launch_bounds__(256, 8)
void k_gather(const short* __restrict__ ebuf, const int* __restrict__ offs,
              const int* __restrict__ eidx, float* __restrict__ abuf, int M) {
    int w = threadIdx.x >> 6, lane = threadIdx.x & 63;
    int a = blockIdx.x * 4 + w;
    if (a >= M) return;
    int s = offs[a], e1 = offs[a + 1];
    float s0 = 0.f, s1 = 0.f;
    for (int p = s; p < e1; ++p) {
        int e = eidx[p];
        unsigned v = *(const unsigned*)&ebuf[(size_t)e * D + lane * 2];
        s0 += bflo(v);
        s1 += bfhi(v);
    }
    float2* dst = (float2*)&abuf[(size_t)a * D + lane * 2];
    float2 cur = *dst;
    cur.x += s0; cur.y += s1;
    *dst = cur;
}

// ---------------- kernel 4: final agent pass ----------------
__global__ __launch_bounds__(256, 4)
void k_final(const float* __restrict__ abuf, const float* __restrict__ agts,
             const float* __restrict__ Wl,
             const float* __restrict__ gnw, const float* __restrict__ gnb,
             const float* __restrict__ glw, const float* __restrict__ glb,
             float* __restrict__ out, int M, int ntiles) {
    __shared__ TileLDS L;
    int tid = threadIdx.x;
    int lane = tid & 63, w = tid >> 6;
    int lr = lane & 15, kh = lane >> 4;
    int n0 = w * 32;
    short8 fl[2][4];
    load_wset(Wl, 128, n0, lr, kh, fl);
    float gw0 = glw[n0 + lr], gw1 = glw[n0 + 16 + lr];
    float gb0 = glb[n0 + lr], gb1 = glb[n0 + 16 + lr];

    for (int tile = blockIdx.x; tile < ntiles; tile += gridDim.x) {
        long rbase = (long)tile * TM;
        int row = tid >> 2, q4 = tid & 3;
        long r = rbase + row;
        // GN #1: load abuf row-chunk into registers, partials in-thread
        float x[32];
        {
            float s = 0.f, q = 0.f;
            const float4* src = (const float4*)(abuf + (size_t)r * D + q4 * 32);
#pragma unroll
            for (int i = 0; i < 8; ++i) {
                float4 v = (r < M) ? src[i] : make_float4(0.f, 0.f, 0.f, 0.f);
                x[i * 4 + 0] = v.x; x[i * 4 + 1] = v.y; x[i * 4 + 2] = v.z; x[i * 4 + 3] = v.w;
                s += v.x + v.y + v.z + v.w;
                q += v.x * v.x + v.y * v.y + v.z * v.z + v.w * v.w;
            }
            L.red[row][q4][0] = (f32x2){s, q};
        }
        __syncthreads();
        if (tid < TM) {
            float s = 0.f, q = 0.f;
#pragma unroll
            for (int i = 0; i < 4; ++i) { f32x2 v = L.red[tid][i][0]; s += v[0]; q += v[1]; }
            float mu = s * (1.f / 128.f);
            float var = q * (1.f / 128.f) - mu * mu;
            L.mr[tid] = (f32x2){mu, rsqrtf(var + 1e-5f)};
        }
        __syncthreads();
        // normalize -> relu -> bf16 A
        {
            f32x2 m = L.mr[row];
#pragma unroll
            for (int cb = 0; cb < 4; ++cb) {
                short8 ov;
#pragma unroll
                for (int j = 0; j < 8; ++j) {
                    int c = q4 * 32 + cb * 8 + j;
                    float v = (x[cb * 8 + j] - m[0]) * m[1] * gnw[c] + gnb[c];
                    ov[j] = f2bf(fmaxf(v, 0.f));
                }
                *(short8*)&L.A[row * APITCH + q4 * 32 + cb * 8] = ov;
            }
        }
        __syncthreads();
        f32x4 acc[4][2];
        wave_gemm(L.A, fl, lr, kh, acc);       // @ Wl^T
        gn_stats(L, acc, tid, lane, w);        // GN #2 stats
        // normalize + residual + relu -> out
#pragma unroll
        for (int mt = 0; mt < 4; ++mt)
#pragma unroll
            for (int rr = 0; rr < 4; ++rr) {
                int orow = mt * 16 + kh * 4 + rr;
                long gr = rbase + orow;
                if (gr < M) {
                    f32x2 m = L.mr[orow];
                    float v0 = (acc[mt][0][rr] - m[0]) * m[1] * gw0 + gb0;
                    float v1 = (acc[mt][1][rr] - m[0]) * m[1] * gw1 + gb1;
                    v0 += agts[(size_t)gr * D + n0 + lr];
                    v1 += agts[(size_t)gr * D + n0 + 16 + lr];
                    out[(size_t)gr * D + n0 + lr]      = fmaxf(v0, 0.f);
                    out[(size_t)gr * D + n0 + 16 + lr] = fmaxf(v1, 0.f);
                }
            }
        __syncthreads();
    }
}

extern "C" void kernel_launch(void* const* d_in, const int* in_sizes, int n_in,
                              void* d_out, int out_size, void* d_ws, size_t ws_size,
                              hipStream_t stream) {
    const float* agts     = (const float*)d_in[0];
    const float* ctx      = (const float*)d_in[1];
    const float* agt_ctrs = (const float*)d_in[2];
    const float* ctx_ctrs = (const float*)d_in[3];
    const int*   hi       = (const int*)d_in[4];
    const int*   wi       = (const int*)d_in[5];
    const float* Wd1 = (const float*)d_in[6];
    const float* bd1 = (const float*)d_in[7];
    const float* Wd2 = (const float*)d_in[8];
    const float* gd2w = (const float*)d_in[9];
    const float* gd2b = (const float*)d_in[10];
    const float* Wq  = (const float*)d_in[11];
    const float* gqw = (const float*)d_in[12];
    const float* gqb = (const float*)d_in[13];
    const float* Wc1 = (const float*)d_in[14];
    const float* gc1w = (const float*)d_in[15];
    const float* gc1b = (const float*)d_in[16];
    const float* Wc2 = (const float*)d_in[17];
    const float* Wa  = (const float*)d_in[18];
    const float* gnw = (const float*)d_in[19];
    const float* gnb = (const float*)d_in[20];
    const float* Wl  = (const float*)d_in[21];
    const float* glw = (const float*)d_in[22];
    const float* glb = (const float*)d_in[23];

    int N_AGT = in_sizes[0] / D;
    int N_CTX = in_sizes[1] / D;
    int E     = in_sizes[4];
    float* out = (float*)d_out;

    // workspace layout
    float* qpart = (float*)d_ws;                       // [N_AGT,128] f32
    float* cpart = qpart + (size_t)N_AGT * D;          // [N_CTX,128] f32
    float* abuf  = cpart + (size_t)N_CTX * D;          // [N_AGT,128] f32
    short* ebuf  = (short*)(abuf + (size_t)N_AGT * D); // [E,128] bf16
    int*   cnt    = (int*)(ebuf + (size_t)E * D);      // [N_AGT]
    int*   offs   = cnt + N_AGT;                       // [N_AGT+1]
    int*   cursor = offs + N_AGT + 1;                  // [N_AGT]
    int*   eidx   = cursor + N_AGT;                    // [E]

    int tq = (N_AGT + TM - 1) / TM;
    int tc = (N_CTX + TM - 1) / TM;
    int te = (E + TM - 1) / TM;
    int ge = (E + 255) / 256;

    hipMemsetAsync(cnt, 0, (size_t)N_AGT * sizeof(int), stream);
    k_hist<<<ge, 256, 0, stream>>>(hi, cnt, E);
    k_scan<<<1, 256, 0, stream>>>(cnt, offs, cursor, N_AGT);
    k_fill<<<ge, 256, 0, stream>>>(hi, cursor, eidx, E);

    k_qpath<<<tq, 256, 0, stream>>>(agts, Wq, gqw, gqb, Wc1, Wa, qpart, abuf, N_AGT, tq);
    k_ctx<<<tc, 256, 0, stream>>>(ctx, Wc1, cpart, N_CTX, tc);
    k_edge<<<te, 256, 0, stream>>>(agt_ctrs, ctx_ctrs, hi, wi, Wd1, bd1,
                                   Wd2, gd2w, gd2b, Wc1, gc1w, gc1b, Wc2,
                                   qpart, cpart, ebuf, E, te);
    k_gather<<<(N_AGT + 3) / 4, 256, 0, stream>>>(ebuf, offs, eidx, abuf, N_AGT);
    k_final<<<tq, 256, 0, stream>>>(abuf, agts, Wl, gnw, gnb, glw, glb, out, N_AGT, tq);
}

// Round 5
// 869.991 us; speedup vs baseline: 1.4579x; 1.4579x over previous
//
#include <hip/hip_runtime.h>
#include <hip/hip_bf16.h>

#define D 128
#define TM 64
#define APITCH 136   // bf16 elems per LDS A row (272B rows -> 2-way bank alias, free)
#define WSLICE 16384 // shorts per packed weight slice (32 slots * 64 lanes * 8)

typedef __attribute__((ext_vector_type(8))) short short8;
typedef __attribute__((ext_vector_type(4))) float f32x4;
typedef __attribute__((ext_vector_type(2))) float f32x2;

__device__ __forceinline__ short f2bf(float f) {
    union { float f; unsigned u; } v; v.f = f;
    unsigned r = v.u + 0x7fffu + ((v.u >> 16) & 1u);  // RNE
    return (short)(r >> 16);
}
__device__ __forceinline__ float bflo(unsigned v) {
    union { unsigned u; float f; } t; t.u = v << 16; return t.f;
}
__device__ __forceinline__ float bfhi(unsigned v) {
    union { unsigned u; float f; } t; t.u = v & 0xffff0000u; return t.f;
}
__device__ __forceinline__ unsigned pkbf(float a, float b) {
    return (unsigned)(unsigned short)f2bf(a) | ((unsigned)(unsigned short)f2bf(b) << 16);
}

struct TileLDS {
    short A[TM * APITCH];     // 17408 B  bf16 A-tile (MFMA A operand)
    f32x2 red[TM][4][4];      // 8192 B   [row][wave][subgroup] partial (sum, sumsq)
    f32x2 mr[TM];             // 512 B    per-row (mean, rstd)
    int hi_s[TM];
    int wi_s[TM];
};

// ---------------- weight pre-pack: f32 row-major -> bf16 fragment layout ----------------
// slot = (w*2+t)*4+ks ; entry [slot][lane] = short8 frag; coalesced 16B/lane reads later.
struct WPA { const float* src[8]; int pitch[8]; int coloff[8]; };

__global__ __launch_bounds__(256)
void k_wprep(WPA a, short* __restrict__ wf) {
    int slice = blockIdx.x & 7, chunk = blockIdx.x >> 3;
    int tid = threadIdx.x, lane = tid & 63;
    int slot = chunk * 4 + (tid >> 6);
    int w = slot >> 3, t = (slot >> 2) & 1, ks = slot & 3;
    int lr = lane & 15, kh = lane >> 4;
    const float* src = a.src[slice];
    int row = w * 32 + t * 16 + lr;
    int col0 = a.coloff[slice] + ks * 32 + kh * 8;
    short8 v;
#pragma unroll
    for (int j = 0; j < 8; ++j) v[j] = f2bf(src[(size_t)row * a.pitch[slice] + col0 + j]);
    *(short8*)&wf[(size_t)slice * WSLICE + ((size_t)slot * 64 + lane) * 8] = v;
}

__device__ __forceinline__ void load_wset_pre(const short* wf, int slice, int w, int lane,
                                              short8 frag[2][4]) {
    const short8* p = (const short8*)(wf + (size_t)slice * WSLICE);
#pragma unroll
    for (int t = 0; t < 2; ++t)
#pragma unroll
        for (int ks = 0; ks < 4; ++ks)
            frag[t][ks] = p[((w * 2 + t) * 4 + ks) * 64 + lane];
}

// Wave computes 64 rows x 32 cols of Y = A(64x128) @ W^T, f32 acc.
__device__ __forceinline__ void wave_gemm(const short* A, const short8 frag[2][4],
                                          int lr, int kh, f32x4 acc[4][2]) {
#pragma unroll
    for (int mt = 0; mt < 4; ++mt)
#pragma unroll
        for (int t = 0; t < 2; ++t)
            acc[mt][t] = (f32x4){0.f, 0.f, 0.f, 0.f};
#pragma unroll
    for (int ks = 0; ks < 4; ++ks) {
        short8 a[4];
#pragma unroll
        for (int mt = 0; mt < 4; ++mt)
            a[mt] = *(const short8*)&A[(mt * 16 + lr) * APITCH + ks * 32 + kh * 8];
#pragma unroll
        for (int mt = 0; mt < 4; ++mt)
#pragma unroll
            for (int t = 0; t < 2; ++t)
                acc[mt][t] = __builtin_amdgcn_mfma_f32_16x16x32_bf16(a[mt], frag[t][ks], acc[mt][t], 0, 0, 0);
    }
}

__device__ __forceinline__ void store_acc_global(float* Y, long rbase, int M,
                                                 const f32x4 acc[4][2], int lane, int w) {
    int lr = lane & 15, hh = lane >> 4;
#pragma unroll
    for (int mt = 0; mt < 4; ++mt)
#pragma unroll
        for (int t = 0; t < 2; ++t)
#pragma unroll
            for (int r = 0; r < 4; ++r) {
                int row = mt * 16 + hh * 4 + r;
                if (rbase + row < M)
                    Y[(size_t)(rbase + row) * D + w * 32 + t * 16 + lr] = acc[mt][t][r];
            }
}

// Store 32-col slice as packed bf16 pairs (col, col+16): u32 at [row][w*16+lr], row stride 64.
__device__ __forceinline__ void store_acc_pk(unsigned* Y, long rbase, int M,
                                             const f32x4 acc[4][2], int lane, int w) {
    int lr = lane & 15, hh = lane >> 4;
#pragma unroll
    for (int mt = 0; mt < 4; ++mt)
#pragma unroll
        for (int r = 0; r < 4; ++r) {
            int row = mt * 16 + hh * 4 + r;
            if (rbase + row < M)
                Y[(size_t)(rbase + row) * 64 + w * 16 + lr] = pkbf(acc[mt][0][r], acc[mt][1][r]);
        }
}

// In-register GN stats from acc -> per-row (mean, rstd) in L.mr. 2 syncthreads.
__device__ __forceinline__ void gn_stats(TileLDS& L, const f32x4 acc[4][2],
                                         int tid, int lane, int w) {
    int lr = lane & 15, hh = lane >> 4;
#pragma unroll
    for (int mt = 0; mt < 4; ++mt)
#pragma unroll
        for (int r = 0; r < 4; ++r) {
            float s = acc[mt][0][r] + acc[mt][1][r];
            float q = acc[mt][0][r] * acc[mt][0][r] + acc[mt][1][r] * acc[mt][1][r];
            s += __shfl_xor(s, 1); q += __shfl_xor(q, 1);
            s += __shfl_xor(s, 2); q += __shfl_xor(q, 2);
            if ((lr & 3) == mt) {
                int row = mt * 16 + hh * 4 + r;
                L.red[row][w][lr >> 2] = (f32x2){s, q};
            }
        }
    __syncthreads();
    if (tid < TM) {
        float s = 0.f, q = 0.f;
        const f32x2* p = (const f32x2*)L.red[tid];
#pragma unroll
        for (int i = 0; i < 16; ++i) { f32x2 v = p[i]; s += v[0]; q += v[1]; }
        float mu = s * (1.f / 128.f);
        float var = q * (1.f / 128.f) - mu * mu;
        L.mr[tid] = (f32x2){mu, rsqrtf(var + 1e-5f)};
    }
    __syncthreads();
}

// Full in-register GN: stats + normalize + relu + write bf16 A-tile. 3 syncs total.
__device__ __forceinline__ void gn_reg(TileLDS& L, const f32x4 acc[4][2],
                                       float gw0, float gb0, float gw1, float gb1,
                                       int tid, int lane, int w) {
    gn_stats(L, acc, tid, lane, w);
    int lr = lane & 15, hh = lane >> 4, n0 = w * 32;
#pragma unroll
    for (int mt = 0; mt < 4; ++mt)
#pragma unroll
        for (int r = 0; r < 4; ++r) {
            int row = mt * 16 + hh * 4 + r;
            f32x2 m = L.mr[row];
            float v0 = (acc[mt][0][r] - m[0]) * m[1] * gw0 + gb0;
            float v1 = (acc[mt][1][r] - m[0]) * m[1] * gw1 + gb1;
            L.A[row * APITCH + n0 + lr]      = f2bf(fmaxf(v0, 0.f));
            L.A[row * APITCH + n0 + 16 + lr] = f2bf(fmaxf(v1, 0.f));
        }
    __syncthreads();
}

__device__ __forceinline__ void stage_rows_to_A(TileLDS& L, const float* X, long rbase, int M, int tid) {
#pragma unroll
    for (int it = 0; it < 8; ++it) {
        int chunk = tid + it * 256;
        int row = chunk >> 5, c4 = chunk & 31;
        long r = rbase + row;
        float4 v = (r < M) ? *(const float4*)&X[(size_t)r * D + c4 * 4] : make_float4(0.f, 0.f, 0.f, 0.f);
        short* a = &L.A[row * APITCH + c4 * 4];
        a[0] = f2bf(v.x); a[1] = f2bf(v.y); a[2] = f2bf(v.z); a[3] = f2bf(v.w);
    }
}

// ---------------- CSR build: histogram -> scan -> fill ----------------
__global__ void k_hist(const int* __restrict__ hi, int* __restrict__ cnt, int E) {
    int i = blockIdx.x * 256 + threadIdx.x;
    if (i < E) atomicAdd(&cnt[hi[i]], 1);
}

__global__ void k_scan(const int* __restrict__ cnt, int* __restrict__ offs,
                       int* __restrict__ cursor, int n) {
    __shared__ int wsum[4];
    __shared__ int carry_s;
    int tid = threadIdx.x, lane = tid & 63, w = tid >> 6;
    if (tid == 0) carry_s = 0;
    __syncthreads();
    for (int base = 0; base < n; base += 256) {
        int i = base + tid;
        int v = (i < n) ? cnt[i] : 0;
        int x = v;
#pragma unroll
        for (int d = 1; d < 64; d <<= 1) {
            int t = __shfl_up(x, d);
            if (lane >= d) x += t;
        }
        if (lane == 63) wsum[w] = x;
        __syncthreads();
        int woff = 0;
        for (int j = 0; j < w; ++j) woff += wsum[j];
        int carry = carry_s;
        int excl = carry + woff + x - v;
        if (i < n) { offs[i] = excl; cursor[i] = excl; }
        __syncthreads();
        if (tid == 255) carry_s = carry + woff + x;
        __syncthreads();
    }
    if (tid == 0) offs[n] = carry_s;
}

__global__ void k_fill(const int* __restrict__ hi, int* __restrict__ cursor,
                       int* __restrict__ eidx, int E) {
    int i = blockIdx.x * 256 + threadIdx.x;
    if (i < E) {
        int p = atomicAdd(&cursor[hi[i]], 1);
        eidx[p] = i;
    }
}

// ---------------- kernel 1: agent-side precompute ----------------
// abuf = agts @ Wa^T ; qa = relu(GN(agts @ Wq^T)) ; qp32 = pack(qa @ Wc1_q^T)
__global__ __launch_bounds__(256, 3)
void k_qpath(const float* __restrict__ agts, const short* __restrict__ wf,
             const float* __restrict__ gqw, const float* __restrict__ gqb,
             unsigned* __restrict__ qp32, float* __restrict__ abuf, int M, int ntiles) {
    __shared__ TileLDS L;
    int tid = threadIdx.x;
    int lane = tid & 63, w = tid >> 6;
    int lr = lane & 15, kh = lane >> 4;
    int n0 = w * 32;
    short8 fa[2][4], fq[2][4], fcq[2][4];
    load_wset_pre(wf, 0, w, lane, fa);
    load_wset_pre(wf, 1, w, lane, fq);
    load_wset_pre(wf, 3, w, lane, fcq);
    float gw0 = gqw[n0 + lr], gw1 = gqw[n0 + 16 + lr];
    float gb0 = gqb[n0 + lr], gb1 = gqb[n0 + 16 + lr];

    for (int tile = blockIdx.x; tile < ntiles; tile += gridDim.x) {
        long rbase = (long)tile * TM;
        stage_rows_to_A(L, agts, rbase, M, tid);
        __syncthreads();
        f32x4 acc[4][2];
        wave_gemm(L.A, fa, lr, kh, acc);
        store_acc_global(abuf, rbase, M, acc, lane, w);
        wave_gemm(L.A, fq, lr, kh, acc);
        gn_reg(L, acc, gw0, gb0, gw1, gb1, tid, lane, w);
        wave_gemm(L.A, fcq, lr, kh, acc);
        store_acc_pk(qp32, rbase, M, acc, lane, w);
        __syncthreads();
    }
}

// ---------------- kernel 2: ctx precompute ----------------
__global__ __launch_bounds__(256, 4)
void k_ctx(const float* __restrict__ ctx, const short* __restrict__ wf,
           unsigned* __restrict__ cp32, int M, int ntiles) {
    __shared__ TileLDS L;
    int tid = threadIdx.x;
    int lane = tid & 63, w = tid >> 6;
    int lr = lane & 15, kh = lane >> 4;
    short8 fc[2][4];
    load_wset_pre(wf, 4, w, lane, fc);
    for (int tile = blockIdx.x; tile < ntiles; tile += gridDim.x) {
        long rbase = (long)tile * TM;
        stage_rows_to_A(L, ctx, rbase, M, tid);
        __syncthreads();
        f32x4 acc[4][2];
        wave_gemm(L.A, fc, lr, kh, acc);
        store_acc_pk(cp32, rbase, M, acc, lane, w);
        __syncthreads();
    }
}

// ---------------- kernel 3: fused edge pipeline (atomic-free, persistent) ----------------
__global__ __launch_bounds__(256, 3)
void k_edge(const float* __restrict__ agt_ctrs, const float* __restrict__ ctx_ctrs,
            const int* __restrict__ hi, const int* __restrict__ wi,
            const float* __restrict__ Wd1, const float* __restrict__ bd1,
            const short* __restrict__ wf,
            const float* __restrict__ gd2w, const float* __restrict__ gd2b,
            const float* __restrict__ gc1w, const float* __restrict__ gc1b,
            const unsigned* __restrict__ qp32, const unsigned* __restrict__ cp32,
            short* __restrict__ ebuf, int E, int ntiles) {
    __shared__ TileLDS L;
    int tid = threadIdx.x;
    int lane = tid & 63, w = tid >> 6;
    int lr = lane & 15, kh = lane >> 4;
    int n0 = w * 32;
    short8 fd2[2][4], fc1[2][4], fc2[2][4];
    load_wset_pre(wf, 5, w, lane, fd2);
    load_wset_pre(wf, 2, w, lane, fc1);
    load_wset_pre(wf, 6, w, lane, fc2);
    float g2w0 = gd2w[n0 + lr], g2w1 = gd2w[n0 + 16 + lr];
    float g2b0 = gd2b[n0 + lr], g2b1 = gd2b[n0 + 16 + lr];
    float g1w0 = gc1w[n0 + lr], g1w1 = gc1w[n0 + 16 + lr];
    float g1b0 = gc1b[n0 + lr], g1b1 = gc1b[n0 + 16 + lr];

    for (int tile = blockIdx.x; tile < ntiles; tile += gridDim.x) {
        long ebase = (long)tile * TM;
        if (tid < TM) {
            long e = ebase + tid;
            L.hi_s[tid] = (e < E) ? hi[e] : 0;
            L.wi_s[tid] = (e < E) ? wi[e] : 0;
        }
        // d2 = relu(dd @ Wd1^T + bd1) -> bf16 A-tile (thread: one row, 32 chans)
        {
            int row = tid >> 2, q4 = tid & 3;
            long e = ebase + row;
            bool valid = e < E;
            float dd0 = 0.f, dd1 = 0.f;
            if (valid) {
                int h = hi[e], c = wi[e];
                dd0 = agt_ctrs[h * 2 + 0] - ctx_ctrs[c * 2 + 0];
                dd1 = agt_ctrs[h * 2 + 1] - ctx_ctrs[c * 2 + 1];
            }
#pragma unroll
            for (int cb = 0; cb < 4; ++cb) {
                short8 ov;
#pragma unroll
                for (int j = 0; j < 8; ++j) {
                    int c = q4 * 32 + cb * 8 + j;
                    float v = valid ? fmaxf(Wd1[c * 2 + 0] * dd0 + Wd1[c * 2 + 1] * dd1 + bd1[c], 0.f) : 0.f;
                    ov[j] = f2bf(v);
                }
                *(short8*)&L.A[row * APITCH + q4 * 32 + cb * 8] = ov;
            }
        }
        __syncthreads();
        f32x4 acc[4][2];
        wave_gemm(L.A, fd2, lr, kh, acc);                 // t = d2 @ Wd2^T
        gn_reg(L, acc, g2w0, g2b0, g2w1, g2b1, tid, lane, w);  // d = relu(GN(t)) -> A
        wave_gemm(L.A, fc1, lr, kh, acc);                 // d @ Wc1_d^T
        // + qp32[hi] + cp32[wi] (packed bf16 pairs, row stride 64 u32)
#pragma unroll
        for (int mt = 0; mt < 4; ++mt)
#pragma unroll
            for (int r = 0; r < 4; ++r) {
                int row = mt * 16 + kh * 4 + r;
                unsigned vq = qp32[(size_t)L.hi_s[row] * 64 + w * 16 + lr];
                unsigned vc = cp32[(size_t)L.wi_s[row] * 64 + w * 16 + lr];
                acc[mt][0][r] += bflo(vq) + bflo(vc);
                acc[mt][1][r] += bfhi(vq) + bfhi(vc);
            }
        gn_reg(L, acc, g1w0, g1b0, g1w1, g1b1, tid, lane, w);  // relu(GN(.)) -> A
        wave_gemm(L.A, fc2, lr, kh, acc);                 // cout = cmid @ Wc2^T
        // store message rows bf16 (fire-and-forget)
#pragma unroll
        for (int mt = 0; mt < 4; ++mt)
#pragma unroll
            for (int r = 0; r < 4; ++r) {
                int erow = mt * 16 + kh * 4 + r;
                long e = ebase + erow;
                if (e < E) {
                    short* dst = ebuf + (size_t)e * D;
                    dst[n0 + lr]      = f2bf(acc[mt][0][r]);
                    dst[n0 + 16 + lr] = f2bf(acc[mt][1][r]);
                }
            }
        __syncthreads();
    }
}

// ---------------- kernel 4: final agent pass (with fused edge-sum gather) ----------------
__global__ __launch_bounds__(256, 4)
void k_final(const float* __restrict__ abuf, const float* __restrict__ agts,
             const short* __restrict__ ebuf, const int* __restrict__ offs,
             const int* __restrict__ eidx, const short* __restrict__ wf,
             const float* __restrict__ gnw, const float* __restrict__ gnb,
             const float* __restrict__ glw, const float* __restrict__ glb,
             float* __restrict__ out, int M, int ntiles) {
    __shared__ TileLDS L;
    int tid = threadIdx.x;
    int lane = tid & 63, w = tid >> 6;
    int lr = lane & 15, kh = lane >> 4;
    int n0 = w * 32;
    short8 fl[2][4];
    load_wset_pre(wf, 7, w, lane, fl);
    float gw0 = glw[n0 + lr], gw1 = glw[n0 + 16 + lr];
    float gb0 = glb[n0 + lr], gb1 = glb[n0 + 16 + lr];

    for (int tile = blockIdx.x; tile < ntiles; tile += gridDim.x) {
        long rbase = (long)tile * TM;
        int row = tid >> 2, q4 = tid & 3;
        long r = rbase + row;
        // a-row = abuf row + sum of incoming edge messages (CSR), then GN #1
        float x[32];
        {
            const float4* src = (const float4*)(abuf + (size_t)r * D + q4 * 32);
#pragma unroll
            for (int i = 0; i < 8; ++i) {
                float4 v = (r < M) ? src[i] : make_float4(0.f, 0.f, 0.f, 0.f);
                x[i * 4 + 0] = v.x; x[i * 4 + 1] = v.y; x[i * 4 + 2] = v.z; x[i * 4 + 3] = v.w;
            }
            if (r < M) {
                int s0 = offs[r], e1 = offs[r + 1];
                for (int p = s0; p < e1; ++p) {
                    int e = eidx[p];
                    const unsigned* er = (const unsigned*)(ebuf + (size_t)e * D + q4 * 32);
#pragma unroll
                    for (int j = 0; j < 16; ++j) {
                        unsigned v = er[j];
                        x[j * 2 + 0] += bflo(v);
                        x[j * 2 + 1] += bfhi(v);
                    }
                }
            }
            float s = 0.f, q = 0.f;
#pragma unroll
            for (int i = 0; i < 32; ++i) { s += x[i]; q += x[i] * x[i]; }
            L.red[row][q4][0] = (f32x2){s, q};
        }
        __syncthreads();
        if (tid < TM) {
            float s = 0.f, q = 0.f;
#pragma unroll
            for (int i = 0; i < 4; ++i) { f32x2 v = L.red[tid][i][0]; s += v[0]; q += v[1]; }
            float mu = s * (1.f / 128.f);
            float var = q * (1.f / 128.f) - mu * mu;
            L.mr[tid] = (f32x2){mu, rsqrtf(var + 1e-5f)};
        }
        __syncthreads();
        // normalize -> relu -> bf16 A
        {
            f32x2 m = L.mr[row];
#pragma unroll
            for (int cb = 0; cb < 4; ++cb) {
                short8 ov;
#pragma unroll
                for (int j = 0; j < 8; ++j) {
                    int c = q4 * 32 + cb * 8 + j;
                    float v = (x[cb * 8 + j] - m[0]) * m[1] * gnw[c] + gnb[c];
                    ov[j] = f2bf(fmaxf(v, 0.f));
                }
                *(short8*)&L.A[row * APITCH + q4 * 32 + cb * 8] = ov;
            }
        }
        __syncthreads();
        f32x4 acc[4][2];
        wave_gemm(L.A, fl, lr, kh, acc);       // @ Wl^T
        gn_stats(L, acc, tid, lane, w);        // GN #2 stats
        // normalize + residual + relu -> out
#pragma unroll
        for (int mt = 0; mt < 4; ++mt)
#pragma unroll
            for (int rr = 0; rr < 4; ++rr) {
                int orow = mt * 16 + kh * 4 + rr;
                long gr = rbase + orow;
                if (gr < M) {
                    f32x2 m = L.mr[orow];
                    float v0 = (acc[mt][0][rr] - m[0]) * m[1] * gw0 + gb0;
                    float v1 = (acc[mt][1][rr] - m[0]) * m[1] * gw1 + gb1;
                    v0 += agts[(size_t)gr * D + n0 + lr];
                    v1 += agts[(size_t)gr * D + n0 + 16 + lr];
                    out[(size_t)gr * D + n0 + lr]      = fmaxf(v0, 0.f);
                    out[(size_t)gr * D + n0 + 16 + lr] = fmaxf(v1, 0.f);
                }
            }
        __syncthreads();
    }
}

extern "C" void kernel_launch(void* const* d_in, const int* in_sizes, int n_in,
                              void* d_out, int out_size, void* d_ws, size_t ws_size,
                              hipStream_t stream) {
    const float* agts     = (const float*)d_in[0];
    const float* ctx      = (const float*)d_in[1];
    const float* agt_ctrs = (const float*)d_in[2];
    const float* ctx_ctrs = (const float*)d_in[3];
    const int*   hi       = (const int*)d_in[4];
    const int*   wi       = (const int*)d_in[5];
    const float* Wd1 = (const float*)d_in[6];
    const float* bd1 = (const float*)d_in[7];
    const float* Wd2 = (const float*)d_in[8];
    const float* gd2w = (const float*)d_in[9];
    const float* gd2b = (const float*)d_in[10];
    const float* Wq  = (const float*)d_in[11];
    const float* gqw = (const float*)d_in[12];
    const float* gqb = (const float*)d_in[13];
    const float* Wc1 = (const float*)d_in[14];
    const float* gc1w = (const float*)d_in[15];
    const float* gc1b = (const float*)d_in[16];
    const float* Wc2 = (const float*)d_in[17];
    const float* Wa  = (const float*)d_in[18];
    const float* gnw = (const float*)d_in[19];
    const float* gnb = (const float*)d_in[20];
    const float* Wl  = (const float*)d_in[21];
    const float* glw = (const float*)d_in[22];
    const float* glb = (const float*)d_in[23];

    int N_AGT = in_sizes[0] / D;
    int N_CTX = in_sizes[1] / D;
    int E     = in_sizes[4];
    float* out = (float*)d_out;

    // workspace layout
    short*    wf   = (short*)d_ws;                          // 8 * 16384 shorts = 256 KB
    unsigned* qp32 = (unsigned*)(wf + 8 * WSLICE);          // [N_AGT][64] packed bf16 pairs
    unsigned* cp32 = qp32 + (size_t)N_AGT * 64;             // [N_CTX][64]
    float*    abuf = (float*)(cp32 + (size_t)N_CTX * 64);   // [N_AGT][128] f32
    short*    ebuf = (short*)(abuf + (size_t)N_AGT * D);    // [E][128] bf16
    int*      cnt    = (int*)(ebuf + (size_t)E * D);        // [N_AGT]
    int*      offs   = cnt + N_AGT;                         // [N_AGT+1]
    int*      cursor = offs + N_AGT + 1;                    // [N_AGT]
    int*      eidx   = cursor + N_AGT;                      // [E]

    int tq = (N_AGT + TM - 1) / TM;
    int tc = (N_CTX + TM - 1) / TM;
    int te = (E + TM - 1) / TM;
    int ge = (E + 255) / 256;
    int gq = tq < 768 ? tq : 768;
    int gc = tc < 768 ? tc : 768;
    int gE = te < 1536 ? te : 1536;
    int gf = tq < 768 ? tq : 768;

    WPA wpa;
    wpa.src[0] = Wa;  wpa.pitch[0] = 128; wpa.coloff[0] = 0;
    wpa.src[1] = Wq;  wpa.pitch[1] = 128; wpa.coloff[1] = 0;
    wpa.src[2] = Wc1; wpa.pitch[2] = 384; wpa.coloff[2] = 0;    // d-part
    wpa.src[3] = Wc1; wpa.pitch[3] = 384; wpa.coloff[3] = 128;  // q-part
    wpa.src[4] = Wc1; wpa.pitch[4] = 384; wpa.coloff[4] = 256;  // ctx-part
    wpa.src[5] = Wd2; wpa.pitch[5] = 128; wpa.coloff[5] = 0;
    wpa.src[6] = Wc2; wpa.pitch[6] = 128; wpa.coloff[6] = 0;
    wpa.src[7] = Wl;  wpa.pitch[7] = 128; wpa.coloff[7] = 0;

    hipMemsetAsync(cnt, 0, (size_t)N_AGT * sizeof(int), stream);
    k_wprep<<<64, 256, 0, stream>>>(wpa, wf);
    k_hist<<<ge, 256, 0, stream>>>(hi, cnt, E);
    k_scan<<<1, 256, 0, stream>>>(cnt, offs, cursor, N_AGT);
    k_fill<<<ge, 256, 0, stream>>>(hi, cursor, eidx, E);

    k_qpath<<<gq, 256, 0, stream>>>(agts, wf, gqw, gqb, qp32, abuf, N_AGT, tq);
    k_ctx<<<gc, 256, 0, stream>>>(ctx, wf, cp32, N_CTX, tc);
    k_edge<<<gE, 256, 0, stream>>>(agt_ctrs, ctx_ctrs, hi, wi, Wd1, bd1, wf,
                                   gd2w, gd2b, gc1w, gc1b, qp32, cp32, ebuf, E, te);
    k_final<<<gf, 256, 0, stream>>>(abuf, agts, ebuf, offs, eidx, wf,
                                    gnw, gnb, glw, glb, out, N_AGT, tq);
}

// Round 6
// 859.406 us; speedup vs baseline: 1.4759x; 1.0123x over previous
//
#include <hip/hip_runtime.h>
#include <hip/hip_bf16.h>

#define D 128
#define TM 64
#define APITCH 136   // bf16 elems per LDS A row (272B rows -> 2-way bank alias, free)
#define WSLICE 16384 // shorts per packed weight slice (32 slots * 64 lanes * 8)

typedef __attribute__((ext_vector_type(8))) short short8;
typedef __attribute__((ext_vector_type(4))) float f32x4;
typedef __attribute__((ext_vector_type(2))) float f32x2;

__device__ __forceinline__ short f2bf(float f) {
    union { float f; unsigned u; } v; v.f = f;
    unsigned r = v.u + 0x7fffu + ((v.u >> 16) & 1u);  // RNE
    return (short)(r >> 16);
}
__device__ __forceinline__ float bflo(unsigned v) {
    union { unsigned u; float f; } t; t.u = v << 16; return t.f;
}
__device__ __forceinline__ float bfhi(unsigned v) {
    union { unsigned u; float f; } t; t.u = v & 0xffff0000u; return t.f;
}
__device__ __forceinline__ unsigned pkbf(float a, float b) {
    return (unsigned)(unsigned short)f2bf(a) | ((unsigned)(unsigned short)f2bf(b) << 16);
}

struct TileLDS {
    short A[TM * APITCH];     // 17408 B  bf16 A-tile (MFMA A operand)
    f32x2 red[TM][4][4];      // 8192 B   [row][wave][subgroup] partial (sum, sumsq)
    f32x2 mr[TM];             // 512 B    per-row (mean, rstd)
    int hi_s[TM];
    int wi_s[TM];
};

// ---------------- weight pre-pack: f32 row-major -> bf16 fragment layout ----------------
struct WPA { const float* src[8]; int pitch[8]; int coloff[8]; };

__global__ __launch_bounds__(256)
void k_wprep(WPA a, short* __restrict__ wf) {
    int slice = blockIdx.x & 7, chunk = blockIdx.x >> 3;
    int tid = threadIdx.x, lane = tid & 63;
    int slot = chunk * 4 + (tid >> 6);
    int w = slot >> 3, t = (slot >> 2) & 1, ks = slot & 3;
    int lr = lane & 15, kh = lane >> 4;
    const float* src = a.src[slice];
    int row = w * 32 + t * 16 + lr;
    int col0 = a.coloff[slice] + ks * 32 + kh * 8;
    short8 v;
#pragma unroll
    for (int j = 0; j < 8; ++j) v[j] = f2bf(src[(size_t)row * a.pitch[slice] + col0 + j]);
    *(short8*)&wf[(size_t)slice * WSLICE + ((size_t)slot * 64 + lane) * 8] = v;
}

__device__ __forceinline__ void load_wset_pre(const short* wf, int slice, int w, int lane,
                                              short8 frag[2][4]) {
    const short8* p = (const short8*)(wf + (size_t)slice * WSLICE);
#pragma unroll
    for (int t = 0; t < 2; ++t)
#pragma unroll
        for (int ks = 0; ks < 4; ++ks)
            frag[t][ks] = p[((w * 2 + t) * 4 + ks) * 64 + lane];
}

// Wave computes 64 rows x 32 cols of Y = A(64x128) @ W^T, f32 acc.
__device__ __forceinline__ void wave_gemm(const short* A, const short8 frag[2][4],
                                          int lr, int kh, f32x4 acc[4][2]) {
#pragma unroll
    for (int mt = 0; mt < 4; ++mt)
#pragma unroll
        for (int t = 0; t < 2; ++t)
            acc[mt][t] = (f32x4){0.f, 0.f, 0.f, 0.f};
#pragma unroll
    for (int ks = 0; ks < 4; ++ks) {
        short8 a[4];
#pragma unroll
        for (int mt = 0; mt < 4; ++mt)
            a[mt] = *(const short8*)&A[(mt * 16 + lr) * APITCH + ks * 32 + kh * 8];
#pragma unroll
        for (int mt = 0; mt < 4; ++mt)
#pragma unroll
            for (int t = 0; t < 2; ++t)
                acc[mt][t] = __builtin_amdgcn_mfma_f32_16x16x32_bf16(a[mt], frag[t][ks], acc[mt][t], 0, 0, 0);
    }
}

__device__ __forceinline__ void store_acc_global(float* Y, long rbase, int M,
                                                 const f32x4 acc[4][2], int lane, int w) {
    int lr = lane & 15, hh = lane >> 4;
#pragma unroll
    for (int mt = 0; mt < 4; ++mt)
#pragma unroll
        for (int t = 0; t < 2; ++t)
#pragma unroll
            for (int r = 0; r < 4; ++r) {
                int row = mt * 16 + hh * 4 + r;
                if (rbase + row < M)
                    Y[(size_t)(rbase + row) * D + w * 32 + t * 16 + lr] = acc[mt][t][r];
            }
}

// Store 32-col slice as packed bf16 pairs (col, col+16): u32 at [row][w*16+lr], row stride 64.
__device__ __forceinline__ void store_acc_pk(unsigned* Y, long rbase, int M,
                                             const f32x4 acc[4][2], int lane, int w) {
    int lr = lane & 15, hh = lane >> 4;
#pragma unroll
    for (int mt = 0; mt < 4; ++mt)
#pragma unroll
        for (int r = 0; r < 4; ++r) {
            int row = mt * 16 + hh * 4 + r;
            if (rbase + row < M)
                Y[(size_t)(rbase + row) * 64 + w * 16 + lr] = pkbf(acc[mt][0][r], acc[mt][1][r]);
        }
}

// In-register GN stats from acc -> per-row (mean, rstd) in L.mr. 2 syncthreads.
__device__ __forceinline__ void gn_stats(TileLDS& L, const f32x4 acc[4][2],
                                         int tid, int lane, int w) {
    int lr = lane & 15, hh = lane >> 4;
#pragma unroll
    for (int mt = 0; mt < 4; ++mt)
#pragma unroll
        for (int r = 0; r < 4; ++r) {
            float s = acc[mt][0][r] + acc[mt][1][r];
            float q = acc[mt][0][r] * acc[mt][0][r] + acc[mt][1][r] * acc[mt][1][r];
            s += __shfl_xor(s, 1); q += __shfl_xor(q, 1);
            s += __shfl_xor(s, 2); q += __shfl_xor(q, 2);
            if ((lr & 3) == mt) {
                int row = mt * 16 + hh * 4 + r;
                L.red[row][w][lr >> 2] = (f32x2){s, q};
            }
        }
    __syncthreads();
    if (tid < TM) {
        float s = 0.f, q = 0.f;
        const f32x2* p = (const f32x2*)L.red[tid];
#pragma unroll
        for (int i = 0; i < 16; ++i) { f32x2 v = p[i]; s += v[0]; q += v[1]; }
        float mu = s * (1.f / 128.f);
        float var = q * (1.f / 128.f) - mu * mu;
        L.mr[tid] = (f32x2){mu, rsqrtf(var + 1e-5f)};
    }
    __syncthreads();
}

// Full in-register GN: stats + normalize + relu + write bf16 A-tile. 3 syncs total.
__device__ __forceinline__ void gn_reg(TileLDS& L, const f32x4 acc[4][2],
                                       float gw0, float gb0, float gw1, float gb1,
                                       int tid, int lane, int w) {
    gn_stats(L, acc, tid, lane, w);
    int lr = lane & 15, hh = lane >> 4, n0 = w * 32;
#pragma unroll
    for (int mt = 0; mt < 4; ++mt)
#pragma unroll
        for (int r = 0; r < 4; ++r) {
            int row = mt * 16 + hh * 4 + r;
            f32x2 m = L.mr[row];
            float v0 = (acc[mt][0][r] - m[0]) * m[1] * gw0 + gb0;
            float v1 = (acc[mt][1][r] - m[0]) * m[1] * gw1 + gb1;
            L.A[row * APITCH + n0 + lr]      = f2bf(fmaxf(v0, 0.f));
            L.A[row * APITCH + n0 + 16 + lr] = f2bf(fmaxf(v1, 0.f));
        }
    __syncthreads();
}

__device__ __forceinline__ void stage_rows_to_A(TileLDS& L, const float* X, long rbase, int M, int tid) {
#pragma unroll
    for (int it = 0; it < 8; ++it) {
        int chunk = tid + it * 256;
        int row = chunk >> 5, c4 = chunk & 31;
        long r = rbase + row;
        float4 v = (r < M) ? *(const float4*)&X[(size_t)r * D + c4 * 4] : make_float4(0.f, 0.f, 0.f, 0.f);
        short* a = &L.A[row * APITCH + c4 * 4];
        a[0] = f2bf(v.x); a[1] = f2bf(v.y); a[2] = f2bf(v.z); a[3] = f2bf(v.w);
    }
}

// ---------------- CSR build: histogram -> scan -> fill (sorted edge copies) ----------------
__global__ void k_hist(const int* __restrict__ hi, int* __restrict__ cnt, int E) {
    int i = blockIdx.x * 256 + threadIdx.x;
    if (i < E) atomicAdd(&cnt[hi[i]], 1);
}

__global__ void k_scan(const int* __restrict__ cnt, int* __restrict__ offs,
                       int* __restrict__ cursor, int n) {
    __shared__ int wsum[4];
    __shared__ int carry_s;
    int tid = threadIdx.x, lane = tid & 63, w = tid >> 6;
    if (tid == 0) carry_s = 0;
    __syncthreads();
    for (int base = 0; base < n; base += 256) {
        int i = base + tid;
        int v = (i < n) ? cnt[i] : 0;
        int x = v;
#pragma unroll
        for (int d = 1; d < 64; d <<= 1) {
            int t = __shfl_up(x, d);
            if (lane >= d) x += t;
        }
        if (lane == 63) wsum[w] = x;
        __syncthreads();
        int woff = 0;
        for (int j = 0; j < w; ++j) woff += wsum[j];
        int carry = carry_s;
        int excl = carry + woff + x - v;
        if (i < n) { offs[i] = excl; cursor[i] = excl; }
        __syncthreads();
        if (tid == 255) carry_s = carry + woff + x;
        __syncthreads();
    }
    if (tid == 0) offs[n] = carry_s;
}

// Emit agent-sorted endpoint arrays: edge at sorted slot p has endpoints hi_srt[p], wi_srt[p].
__global__ void k_fill(const int* __restrict__ hi, const int* __restrict__ wi,
                       int* __restrict__ cursor,
                       int* __restrict__ hi_srt, int* __restrict__ wi_srt, int E) {
    int i = blockIdx.x * 256 + threadIdx.x;
    if (i < E) {
        int h = hi[i];
        int p = atomicAdd(&cursor[h], 1);
        hi_srt[p] = h;
        wi_srt[p] = wi[i];
    }
}

// ---------------- kernel 1: agent-side precompute ----------------
__global__ __launch_bounds__(256, 3)
void k_qpath(const float* __restrict__ agts, const short* __restrict__ wf,
             const float* __restrict__ gqw, const float* __restrict__ gqb,
             unsigned* __restrict__ qp32, float* __restrict__ abuf, int M, int ntiles) {
    __shared__ TileLDS L;
    int tid = threadIdx.x;
    int lane = tid & 63, w = tid >> 6;
    int lr = lane & 15, kh = lane >> 4;
    int n0 = w * 32;
    short8 fa[2][4], fq[2][4], fcq[2][4];
    load_wset_pre(wf, 0, w, lane, fa);
    load_wset_pre(wf, 1, w, lane, fq);
    load_wset_pre(wf, 3, w, lane, fcq);
    float gw0 = gqw[n0 + lr], gw1 = gqw[n0 + 16 + lr];
    float gb0 = gqb[n0 + lr], gb1 = gqb[n0 + 16 + lr];

    for (int tile = blockIdx.x; tile < ntiles; tile += gridDim.x) {
        long rbase = (long)tile * TM;
        stage_rows_to_A(L, agts, rbase, M, tid);
        __syncthreads();
        f32x4 acc[4][2];
        wave_gemm(L.A, fa, lr, kh, acc);
        store_acc_global(abuf, rbase, M, acc, lane, w);
        wave_gemm(L.A, fq, lr, kh, acc);
        gn_reg(L, acc, gw0, gb0, gw1, gb1, tid, lane, w);
        wave_gemm(L.A, fcq, lr, kh, acc);
        store_acc_pk(qp32, rbase, M, acc, lane, w);
        __syncthreads();
    }
}

// ---------------- kernel 2: ctx precompute ----------------
__global__ __launch_bounds__(256, 4)
void k_ctx(const float* __restrict__ ctx, const short* __restrict__ wf,
           unsigned* __restrict__ cp32, int M, int ntiles) {
    __shared__ TileLDS L;
    int tid = threadIdx.x;
    int lane = tid & 63, w = tid >> 6;
    int lr = lane & 15, kh = lane >> 4;
    short8 fc[2][4];
    load_wset_pre(wf, 4, w, lane, fc);
    for (int tile = blockIdx.x; tile < ntiles; tile += gridDim.x) {
        long rbase = (long)tile * TM;
        stage_rows_to_A(L, ctx, rbase, M, tid);
        __syncthreads();
        f32x4 acc[4][2];
        wave_gemm(L.A, fc, lr, kh, acc);
        store_acc_pk(cp32, rbase, M, acc, lane, w);
        __syncthreads();
    }
}

// ---------------- kernel 3: fused edge pipeline, agent-sorted order ----------------
__global__ __launch_bounds__(256, 3)
void k_edge(const float* __restrict__ agt_ctrs, const float* __restrict__ ctx_ctrs,
            const int* __restrict__ hi_srt, const int* __restrict__ wi_srt,
            const float* __restrict__ Wd1, const float* __restrict__ bd1,
            const short* __restrict__ wf,
            const float* __restrict__ gd2w, const float* __restrict__ gd2b,
            const float* __restrict__ gc1w, const float* __restrict__ gc1b,
            const unsigned* __restrict__ qp32, const unsigned* __restrict__ cp32,
            unsigned* __restrict__ ebuf32, int E, int ntiles) {
    __shared__ TileLDS L;
    int tid = threadIdx.x;
    int lane = tid & 63, w = tid >> 6;
    int lr = lane & 15, kh = lane >> 4;
    int n0 = w * 32;
    short8 fd2[2][4], fc1[2][4], fc2[2][4];
    load_wset_pre(wf, 5, w, lane, fd2);
    load_wset_pre(wf, 2, w, lane, fc1);
    load_wset_pre(wf, 6, w, lane, fc2);
    float g2w0 = gd2w[n0 + lr], g2w1 = gd2w[n0 + 16 + lr];
    float g2b0 = gd2b[n0 + lr], g2b1 = gd2b[n0 + 16 + lr];
    float g1w0 = gc1w[n0 + lr], g1w1 = gc1w[n0 + 16 + lr];
    float g1b0 = gc1b[n0 + lr], g1b1 = gc1b[n0 + 16 + lr];

    for (int tile = blockIdx.x; tile < ntiles; tile += gridDim.x) {
        long ebase = (long)tile * TM;
        if (tid < TM) {
            long e = ebase + tid;
            L.hi_s[tid] = (e < E) ? hi_srt[e] : 0;
            L.wi_s[tid] = (e < E) ? wi_srt[e] : 0;
        }
        // d2 = relu(dd @ Wd1^T + bd1) -> bf16 A-tile (thread: one row, 32 chans)
        {
            int row = tid >> 2, q4 = tid & 3;
            long e = ebase + row;
            bool valid = e < E;
            float dd0 = 0.f, dd1 = 0.f;
            if (valid) {
                int h = hi_srt[e], c = wi_srt[e];
                dd0 = agt_ctrs[h * 2 + 0] - ctx_ctrs[c * 2 + 0];
                dd1 = agt_ctrs[h * 2 + 1] - ctx_ctrs[c * 2 + 1];
            }
#pragma unroll
            for (int cb = 0; cb < 4; ++cb) {
                short8 ov;
#pragma unroll
                for (int j = 0; j < 8; ++j) {
                    int c = q4 * 32 + cb * 8 + j;
                    float v = valid ? fmaxf(Wd1[c * 2 + 0] * dd0 + Wd1[c * 2 + 1] * dd1 + bd1[c], 0.f) : 0.f;
                    ov[j] = f2bf(v);
                }
                *(short8*)&L.A[row * APITCH + q4 * 32 + cb * 8] = ov;
            }
        }
        __syncthreads();
        f32x4 acc[4][2];
        wave_gemm(L.A, fd2, lr, kh, acc);                 // t = d2 @ Wd2^T
        gn_reg(L, acc, g2w0, g2b0, g2w1, g2b1, tid, lane, w);  // d = relu(GN(t)) -> A
        wave_gemm(L.A, fc1, lr, kh, acc);                 // d @ Wc1_d^T
        // + qp32[hi] (near-sequential, heavy reuse) + cp32[wi] (random)
#pragma unroll
        for (int mt = 0; mt < 4; ++mt)
#pragma unroll
            for (int r = 0; r < 4; ++r) {
                int row = mt * 16 + kh * 4 + r;
                unsigned vq = qp32[(size_t)L.hi_s[row] * 64 + w * 16 + lr];
                unsigned vc = cp32[(size_t)L.wi_s[row] * 64 + w * 16 + lr];
                acc[mt][0][r] += bflo(vq) + bflo(vc);
                acc[mt][1][r] += bfhi(vq) + bfhi(vc);
            }
        gn_reg(L, acc, g1w0, g1b0, g1w1, g1b1, tid, lane, w);  // relu(GN(.)) -> A
        wave_gemm(L.A, fc2, lr, kh, acc);                 // cout = cmid @ Wc2^T
        // store message rows: packed u32, coalesced 64B per 16-lane group, CSR slot order
#pragma unroll
        for (int mt = 0; mt < 4; ++mt)
#pragma unroll
            for (int r = 0; r < 4; ++r) {
                int erow = mt * 16 + kh * 4 + r;
                long e = ebase + erow;
                if (e < E)
                    ebuf32[(size_t)e * 64 + w * 16 + lr] = pkbf(acc[mt][0][r], acc[mt][1][r]);
            }
        __syncthreads();
    }
}

// ---------------- kernel 4: final agent pass (streamed CSR edge-sum) ----------------
__global__ __launch_bounds__(256, 4)
void k_final(const float* __restrict__ abuf, const float* __restrict__ agts,
             const unsigned* __restrict__ ebuf32, const int* __restrict__ offs,
             const short* __restrict__ wf,
             const float* __restrict__ gnw, const float* __restrict__ gnb,
             const float* __restrict__ glw, const float* __restrict__ glb,
             float* __restrict__ out, int M, int ntiles) {
    __shared__ TileLDS L;
    int tid = threadIdx.x;
    int lane = tid & 63, w = tid >> 6;
    int lr = lane & 15, kh = lane >> 4;
    int n0 = w * 32;
    short8 fl[2][4];
    load_wset_pre(wf, 7, w, lane, fl);
    float gw0 = glw[n0 + lr], gw1 = glw[n0 + 16 + lr];
    float gb0 = glb[n0 + lr], gb1 = glb[n0 + 16 + lr];

    for (int tile = blockIdx.x; tile < ntiles; tile += gridDim.x) {
        long rbase = (long)tile * TM;
        int row = tid >> 2, q4 = tid & 3;
        long r = rbase + row;
        // a-row = abuf row + contiguous sum of ebuf rows offs[r]..offs[r+1], then GN #1
        float x[32];
        {
            const float4* src = (const float4*)(abuf + (size_t)r * D + q4 * 32);
#pragma unroll
            for (int i = 0; i < 8; ++i) {
                float4 v = (r < M) ? src[i] : make_float4(0.f, 0.f, 0.f, 0.f);
                x[i * 4 + 0] = v.x; x[i * 4 + 1] = v.y; x[i * 4 + 2] = v.z; x[i * 4 + 3] = v.w;
            }
            if (r < M) {
                int s0 = offs[r], e1 = offs[r + 1];
                for (int p = s0; p < e1; ++p) {
                    const unsigned* er = ebuf32 + (size_t)p * 64 + q4 * 16;
#pragma unroll
                    for (int j = 0; j < 16; ++j) {
                        unsigned v = er[j];
                        x[j]      += bflo(v);   // channel q4*32 + j
                        x[16 + j] += bfhi(v);   // channel q4*32 + 16 + j
                    }
                }
            }
            float s = 0.f, q = 0.f;
#pragma unroll
            for (int i = 0; i < 32; ++i) { s += x[i]; q += x[i] * x[i]; }
            L.red[row][q4][0] = (f32x2){s, q};
        }
        __syncthreads();
        if (tid < TM) {
            float s = 0.f, q = 0.f;
#pragma unroll
            for (int i = 0; i < 4; ++i) { f32x2 v = L.red[tid][i][0]; s += v[0]; q += v[1]; }
            float mu = s * (1.f / 128.f);
            float var = q * (1.f / 128.f) - mu * mu;
            L.mr[tid] = (f32x2){mu, rsqrtf(var + 1e-5f)};
        }
        __syncthreads();
        // normalize -> relu -> bf16 A
        {
            f32x2 m = L.mr[row];
#pragma unroll
            for (int cb = 0; cb < 4; ++cb) {
                short8 ov;
#pragma unroll
                for (int j = 0; j < 8; ++j) {
                    int c = q4 * 32 + cb * 8 + j;
                    float v = (x[cb * 8 + j] - m[0]) * m[1] * gnw[c] + gnb[c];
                    ov[j] = f2bf(fmaxf(v, 0.f));
                }
                *(short8*)&L.A[row * APITCH + q4 * 32 + cb * 8] = ov;
            }
        }
        __syncthreads();
        f32x4 acc[4][2];
        wave_gemm(L.A, fl, lr, kh, acc);       // @ Wl^T
        gn_stats(L, acc, tid, lane, w);        // GN #2 stats
        // normalize + residual + relu -> out
#pragma unroll
        for (int mt = 0; mt < 4; ++mt)
#pragma unroll
            for (int rr = 0; rr < 4; ++rr) {
                int orow = mt * 16 + kh * 4 + rr;
                long gr = rbase + orow;
                if (gr < M) {
                    f32x2 m = L.mr[orow];
                    float v0 = (acc[mt][0][rr] - m[0]) * m[1] * gw0 + gb0;
                    float v1 = (acc[mt][1][rr] - m[0]) * m[1] * gw1 + gb1;
                    v0 += agts[(size_t)gr * D + n0 + lr];
                    v1 += agts[(size_t)gr * D + n0 + 16 + lr];
                    out[(size_t)gr * D + n0 + lr]      = fmaxf(v0, 0.f);
                    out[(size_t)gr * D + n0 + 16 + lr] = fmaxf(v1, 0.f);
                }
            }
        __syncthreads();
    }
}

extern "C" void kernel_launch(void* const* d_in, const int* in_sizes, int n_in,
                              void* d_out, int out_size, void* d_ws, size_t ws_size,
                              hipStream_t stream) {
    const float* agts     = (const float*)d_in[0];
    const float* ctx      = (const float*)d_in[1];
    const float* agt_ctrs = (const float*)d_in[2];
    const float* ctx_ctrs = (const float*)d_in[3];
    const int*   hi       = (const int*)d_in[4];
    const int*   wi       = (const int*)d_in[5];
    const float* Wd1 = (const float*)d_in[6];
    const float* bd1 = (const float*)d_in[7];
    const float* Wd2 = (const float*)d_in[8];
    const float* gd2w = (const float*)d_in[9];
    const float* gd2b = (const float*)d_in[10];
    const float* Wq  = (const float*)d_in[11];
    const float* gqw = (const float*)d_in[12];
    const float* gqb = (const float*)d_in[13];
    const float* Wc1 = (const float*)d_in[14];
    const float* gc1w = (const float*)d_in[15];
    const float* gc1b = (const float*)d_in[16];
    const float* Wc2 = (const float*)d_in[17];
    const float* Wa  = (const float*)d_in[18];
    const float* gnw = (const float*)d_in[19];
    const float* gnb = (const float*)d_in[20];
    const float* Wl  = (const float*)d_in[21];
    const float* glw = (const float*)d_in[22];
    const float* glb = (const float*)d_in[23];

    int N_AGT = in_sizes[0] / D;
    int N_CTX = in_sizes[1] / D;
    int E     = in_sizes[4];
    float* out = (float*)d_out;

    // workspace layout
    short*    wf     = (short*)d_ws;                        // 256 KB
    unsigned* qp32   = (unsigned*)(wf + 8 * WSLICE);        // [N_AGT][64] packed bf16 pairs
    unsigned* cp32   = qp32 + (size_t)N_AGT * 64;           // [N_CTX][64]
    float*    abuf   = (float*)(cp32 + (size_t)N_CTX * 64); // [N_AGT][128] f32
    unsigned* ebuf32 = (unsigned*)(abuf + (size_t)N_AGT * D); // [E][64] packed bf16 pairs
    int*      cnt    = (int*)(ebuf32 + (size_t)E * 64);     // [N_AGT]
    int*      offs   = cnt + N_AGT;                         // [N_AGT+1]
    int*      cursor = offs + N_AGT + 1;                    // [N_AGT]
    int*      hi_srt = cursor + N_AGT;                      // [E]
    int*      wi_srt = hi_srt + E;                          // [E]

    int tq = (N_AGT + TM - 1) / TM;
    int tc = (N_CTX + TM - 1) / TM;
    int te = (E + TM - 1) / TM;
    int ge = (E + 255) / 256;
    int gq = tq < 768 ? tq : 768;
    int gc = tc < 768 ? tc : 768;
    int gE = te < 1536 ? te : 1536;
    int gf = tq < 768 ? tq : 768;

    WPA wpa;
    wpa.src[0] = Wa;  wpa.pitch[0] = 128; wpa.coloff[0] = 0;
    wpa.src[1] = Wq;  wpa.pitch[1] = 128; wpa.coloff[1] = 0;
    wpa.src[2] = Wc1; wpa.pitch[2] = 384; wpa.coloff[2] = 0;    // d-part
    wpa.src[3] = Wc1; wpa.pitch[3] = 384; wpa.coloff[3] = 128;  // q-part
    wpa.src[4] = Wc1; wpa.pitch[4] = 384; wpa.coloff[4] = 256;  // ctx-part
    wpa.src[5] = Wd2; wpa.pitch[5] = 128; wpa.coloff[5] = 0;
    wpa.src[6] = Wc2; wpa.pitch[6] = 128; wpa.coloff[6] = 0;
    wpa.src[7] = Wl;  wpa.pitch[7] = 128; wpa.coloff[7] = 0;

    hipMemsetAsync(cnt, 0, (size_t)N_AGT * sizeof(int), stream);
    k_wprep<<<64, 256, 0, stream>>>(wpa, wf);
    k_hist<<<ge, 256, 0, stream>>>(hi, cnt, E);
    k_scan<<<1, 256, 0, stream>>>(cnt, offs, cursor, N_AGT);
    k_fill<<<ge, 256, 0, stream>>>(hi, wi, cursor, hi_srt, wi_srt, E);

    k_qpath<<<gq, 256, 0, stream>>>(agts, wf, gqw, gqb, qp32, abuf, N_AGT, tq);
    k_ctx<<<gc, 256, 0, stream>>>(ctx, wf, cp32, N_CTX, tc);
    k_edge<<<gE, 256, 0, stream>>>(agt_ctrs, ctx_ctrs, hi_srt, wi_srt, Wd1, bd1, wf,
                                   gd2w, gd2b, gc1w, gc1b, qp32, cp32, ebuf32, E, te);
    k_final<<<gf, 256, 0, stream>>>(abuf, agts, ebuf32, offs, wf,
                                    gnw, gnb, glw, glb, out, N_AGT, tq);
}